// Round 1
// baseline (505.300 us; speedup 1.0000x reference)
//
#include <hip/hip_runtime.h>
#include <cstddef>

#define NPTS   2048
#define NBATCH 16
#define MROWS  (NPTS*NBATCH)   // 32768
#define BN_EPS 1e-5f

// ---------------------------------------------------------------------------
// Kernel 1: self_feat = feat @ W_feat + b_feat ; pre_byp = feat @ W_byp
// block = 256 threads = 256 output columns (64 self + 192 byp); 64 rows/block.
// feat row is read via uniform (scalar) loads; W column cached in VGPRs.
// ---------------------------------------------------------------------------
__global__ __launch_bounds__(256) void linear1_k(
    const float* __restrict__ feat, const float* __restrict__ Wf,
    const float* __restrict__ bf,   const float* __restrict__ Wb,
    float* __restrict__ selfF, float* __restrict__ preB)
{
    const int t  = threadIdx.x;
    const int r0 = blockIdx.x * 64;
    const bool isF = (t < 64);
    const int o = isF ? t : (t - 64);

    float wcol[64];
    if (isF) {
        #pragma unroll
        for (int k = 0; k < 64; ++k) wcol[k] = Wf[k*64 + o];
    } else {
        #pragma unroll
        for (int k = 0; k < 64; ++k) wcol[k] = Wb[k*192 + o];
    }
    const float bias = isF ? bf[o] : 0.0f;

    for (int rr = 0; rr < 64; ++rr) {
        const int r = r0 + rr;
        const float* __restrict__ fr = feat + (size_t)r * 64;
        float a = bias;
        #pragma unroll
        for (int k = 0; k < 64; ++k) a = fmaf(wcol[k], fr[k], a);
        if (isF) selfF[(size_t)r*64  + o] = a;
        else     preB [(size_t)r*192 + o] = a;
    }
}

// ---------------------------------------------------------------------------
// Per-channel sum / sumsq (training-mode BN stats). R rows per block-iter,
// thread t -> (row_off = t/C, chan = t%C). Atomic accumulate into ws.
// ---------------------------------------------------------------------------
template<int C, int R>
__global__ __launch_bounds__(256) void stats_k(const float* __restrict__ X, int Mrows,
                                               float* __restrict__ osum, float* __restrict__ osq)
{
    __shared__ float l1[256];
    __shared__ float l2[256];
    const int t = threadIdx.x;
    float ps = 0.0f, pq = 0.0f;
    if (t < C*R) {
        const int c  = t % C;
        const int ro = t / C;
        for (int r = blockIdx.x * R + ro; r < Mrows; r += gridDim.x * R) {
            const float v = X[(size_t)r*C + c];
            ps += v; pq += v*v;
        }
    }
    l1[t] = ps; l2[t] = pq;
    __syncthreads();
    if (t < C) {
        #pragma unroll
        for (int rr = 1; rr < R; ++rr) { ps += l1[t + rr*C]; pq += l2[t + rr*C]; }
        atomicAdd(osum + t, ps);
        atomicAdd(osq  + t, pq);
    }
}

// ---------------------------------------------------------------------------
// y = relu(gamma*(x-mu)*rsqrt(var+eps)+beta), scale/shift computed per block
// from raw sums. float4 elementwise; X may equal Y (in-place).
// ---------------------------------------------------------------------------
template<int C>
__global__ __launch_bounds__(256) void bn_relu_k(
    const float* __restrict__ sum, const float* __restrict__ sq,
    const float* __restrict__ g,   const float* __restrict__ be,
    const float* __restrict__ X, float* __restrict__ Y, int n4)
{
    __shared__ __align__(16) float ssc[C];
    __shared__ __align__(16) float ssh[C];
    const int t = threadIdx.x;
    if (t < C) {
        const float invM = 1.0f / (float)MROWS;
        const float mu  = sum[t] * invM;
        const float var = sq[t] * invM - mu*mu;
        const float sc  = g[t] * rsqrtf(var + BN_EPS);
        ssc[t] = sc;
        ssh[t] = be[t] - mu * sc;
    }
    __syncthreads();
    const float4* __restrict__ X4 = (const float4*)X;
    float4* __restrict__ Y4 = (float4*)Y;
    const int stride = gridDim.x * 256;
    for (int i = blockIdx.x*256 + t; i < n4; i += stride) {
        const int c4 = i % (C/4);
        float4 v = X4[i];
        const float4 sc = ((const float4*)ssc)[c4];
        const float4 sh = ((const float4*)ssh)[c4];
        v.x = fmaxf(fmaf(v.x, sc.x, sh.x), 0.0f);
        v.y = fmaxf(fmaf(v.y, sc.y, sh.y), 0.0f);
        v.z = fmaxf(fmaf(v.z, sc.z, sh.z), 0.0f);
        v.w = fmaxf(fmaf(v.w, sc.w, sh.w), 0.0f);
        Y4[i] = v;
    }
}

// ---------------------------------------------------------------------------
// Aggregate: for each point i, weighted sum over neighbors j.
// Block = 512 threads = 8 waves; block owns 64 i's (lane = i), each wave a
// 256-wide j slice. j-side data (xyz row, mutual row of 192 floats) is
// wave-uniform -> scalar loads feeding v_fma with SGPR operand.
// Grid = 512 = 16 batches x 32 i-tiles, XCD-swizzled (512 % 8 == 0).
// ---------------------------------------------------------------------------
__global__ __launch_bounds__(512) void aggregate_k(
    const float* __restrict__ mutual, const float* __restrict__ xyz,
    float* __restrict__ ag)
{
    __shared__ float lacc[4][64][36];
    __shared__ float lnorm[4][64];

    const int bid = blockIdx.x;
    const int swz = (bid & 7) * 64 + (bid >> 3);   // bijective, 512 blocks
    const int b   = swz >> 5;                      // 0..15
    const int i0  = (swz & 31) << 6;               // 0..2047 step 64
    const int t    = threadIdx.x;
    const int lane = t & 63;
    const int wu   = __builtin_amdgcn_readfirstlane(t >> 6);  // 0..7, uniform

    const float* __restrict__ xb = xyz    + (size_t)b * NPTS * 3;
    const float* __restrict__ mb = mutual + (size_t)b * NPTS * 192;

    const int i = i0 + lane;
    const float xi = xb[(size_t)i*3 + 0];
    const float yi = xb[(size_t)i*3 + 1];
    const float zi = xb[(size_t)i*3 + 2];

    float acc[32];
    #pragma unroll
    for (int c = 0; c < 32; ++c) acc[c] = 0.0f;
    float norm = 0.0f;

    const float r2    = 0.15f * 0.15f;
    const float dr2   = 0.30f * 0.30f;
    const float invdr = 1.0f / (dr2 - r2);

    const int j0 = wu * 256;
    for (int j = j0; j < j0 + 256; ++j) {
        const float xj = xb[j*3 + 0];
        const float yj = xb[j*3 + 1];
        const float zj = xb[j*3 + 2];
        const float dx = xj - xi, dy = yj - yi, dz = zj - zi;
        const float d2 = fmaf(dx, dx, fmaf(dy, dy, dz*dz));
        float wd = (d2 <= r2) ? 1.0f : (dr2 - d2) * invdr;
        const bool valid = (d2 < dr2) && (d2 > 0.0f);
        wd = valid ? wd : 0.0f;
        norm += wd;
        const float inv = wd * __builtin_amdgcn_rcpf(fmaxf(d2, 1e-12f));
        const float wax = inv*dx*dx, way = inv*dy*dy, waz = inv*dz*dz;
        const float wpx = (dx > 0.0f) ? wax : 0.0f; const float wnx = wax - wpx;
        const float wpy = (dy > 0.0f) ? way : 0.0f; const float wny = way - wpy;
        const float wpz = (dz > 0.0f) ? waz : 0.0f; const float wnz = waz - wpz;
        const float* __restrict__ m = mb + (size_t)j * 192;
        #pragma unroll
        for (int c = 0; c < 32; ++c) acc[c] = fmaf(wpx, m[c],       acc[c]);
        #pragma unroll
        for (int c = 0; c < 32; ++c) acc[c] = fmaf(wnx, m[32 + c],  acc[c]);
        #pragma unroll
        for (int c = 0; c < 32; ++c) acc[c] = fmaf(wpy, m[64 + c],  acc[c]);
        #pragma unroll
        for (int c = 0; c < 32; ++c) acc[c] = fmaf(wny, m[96 + c],  acc[c]);
        #pragma unroll
        for (int c = 0; c < 32; ++c) acc[c] = fmaf(wpz, m[128 + c], acc[c]);
        #pragma unroll
        for (int c = 0; c < 32; ++c) acc[c] = fmaf(wnz, m[160 + c], acc[c]);
    }

    // ---- two-stage cross-wave combine (keeps LDS at 38 KB < 64 KB limit) ----
    if (wu >= 4) {
        #pragma unroll
        for (int c = 0; c < 32; ++c) lacc[wu-4][lane][c] = acc[c];
        lnorm[wu-4][lane] = norm;
    }
    __syncthreads();
    if (wu < 4) {
        #pragma unroll
        for (int c = 0; c < 32; ++c) acc[c] += lacc[wu][lane][c];
        norm += lnorm[wu][lane];
        #pragma unroll
        for (int c = 0; c < 32; ++c) lacc[wu][lane][c] = acc[c];
        lnorm[wu][lane] = norm;
    }
    __syncthreads();

    if (t < 256) {
        const int ii = t >> 2;
        const int c0 = (t & 3) << 3;
        float s[8];
        #pragma unroll
        for (int k = 0; k < 8; ++k) s[k] = 0.0f;
        float ns = 0.0f;
        #pragma unroll
        for (int ww = 0; ww < 4; ++ww) {
            ns += lnorm[ww][ii];
            #pragma unroll
            for (int k = 0; k < 8; ++k) s[k] += lacc[ww][ii][c0 + k];
        }
        const float invn = __builtin_amdgcn_rcpf(fmaxf(ns, 1e-12f));
        const size_t base = ((size_t)b*NPTS + i0 + ii) * 32 + c0;
        float4 v0 = { s[0]*invn, s[1]*invn, s[2]*invn, s[3]*invn };
        float4 v1 = { s[4]*invn, s[5]*invn, s[6]*invn, s[7]*invn };
        *(float4*)(ag + base)     = v0;
        *(float4*)(ag + base + 4) = v1;
    }
}

// ---------------------------------------------------------------------------
// Kernel: pre2 = bn1relu(ag) @ W_ag + b_ag + self_feat
// (reads agbn already BN'd in-place). lane = out channel (64), 16 rows/wave.
// ---------------------------------------------------------------------------
__global__ __launch_bounds__(256) void linear2_k(
    const float* __restrict__ agbn, const float* __restrict__ Wag,
    const float* __restrict__ bag,  const float* __restrict__ selfF,
    float* __restrict__ pre2)
{
    const int t  = threadIdx.x;
    const int o  = t & 63;
    const int wu = __builtin_amdgcn_readfirstlane(t >> 6);
    const int r0 = blockIdx.x * 64 + wu * 16;

    float wcol[32];
    #pragma unroll
    for (int k = 0; k < 32; ++k) wcol[k] = Wag[k*64 + o];
    const float bias = bag[o];

    for (int rr = 0; rr < 16; ++rr) {
        const int r = r0 + rr;
        const float* __restrict__ ar = agbn + (size_t)r * 32;
        float a = bias + selfF[(size_t)r*64 + o];
        #pragma unroll
        for (int k = 0; k < 32; ++k) a = fmaf(wcol[k], ar[k], a);
        pre2[(size_t)r*64 + o] = a;
    }
}

// ---------------------------------------------------------------------------
extern "C" void kernel_launch(void* const* d_in, const int* in_sizes, int n_in,
                              void* d_out, int out_size, void* d_ws, size_t ws_size,
                              hipStream_t stream)
{
    const float* feat = (const float*)d_in[0];
    const float* xyz  = (const float*)d_in[1];
    const float* Wf   = (const float*)d_in[2];
    const float* bf   = (const float*)d_in[3];
    const float* Wb   = (const float*)d_in[4];
    const float* gby  = (const float*)d_in[5];
    const float* beby = (const float*)d_in[6];
    const float* g1   = (const float*)d_in[7];
    const float* be1  = (const float*)d_in[8];
    const float* Wag  = (const float*)d_in[9];
    const float* bag  = (const float*)d_in[10];
    const float* g2   = (const float*)d_in[11];
    const float* be2  = (const float*)d_in[12];

    float* ws = (float*)d_ws;
    // ws layout (floats):
    //   [0,1024)            BN stats (sums/sumsqs, atomically accumulated)
    //   A @ 1024            self_feat   [32768 x 64]
    //   B @ A+2097152       pre_byp -> mutual -> (reused) pre2  [32768 x 192]
    //   C @ B+6291456       ag_raw -> ag_bn  [32768 x 32]
    // total ~37.8 MB
    float* stats = ws;
    float* A = ws + 1024;
    float* B = A + (size_t)MROWS * 64;
    float* C = B + (size_t)MROWS * 192;
    float* D = B;   // pre2 reuses B (mutual dead after aggregate)

    float* s192s = stats;       float* s192q = stats + 192;
    float* s32s  = stats + 384; float* s32q  = stats + 416;
    float* s64s  = stats + 448; float* s64q  = stats + 512;

    hipMemsetAsync(stats, 0, 1024 * sizeof(float), stream);

    linear1_k<<<512, 256, 0, stream>>>(feat, Wf, bf, Wb, A, B);

    stats_k<192,1><<<256, 256, 0, stream>>>(B, MROWS, s192s, s192q);
    bn_relu_k<192><<<1024, 256, 0, stream>>>(s192s, s192q, gby, beby, B, B, MROWS*192/4);

    aggregate_k<<<512, 512, 0, stream>>>(B, xyz, C);

    stats_k<32,8><<<256, 256, 0, stream>>>(C, MROWS, s32s, s32q);
    bn_relu_k<32><<<256, 256, 0, stream>>>(s32s, s32q, g1, be1, C, C, MROWS*32/4);

    linear2_k<<<512, 256, 0, stream>>>(C, Wag, bag, A, D);

    stats_k<64,4><<<256, 256, 0, stream>>>(D, MROWS, s64s, s64q);
    bn_relu_k<64><<<512, 256, 0, stream>>>(s64s, s64q, g2, be2, D, (float*)d_out, MROWS*64/4);
}

// Round 3
// 242.994 us; speedup vs baseline: 2.0795x; 2.0795x over previous
//
#include <hip/hip_runtime.h>
#include <cstddef>

#define NPTS   2048
#define NB     16
#define MROWS  (NPTS*NB)   // 32768
#define BN_EPS 1e-5f

typedef __attribute__((ext_vector_type(8))) short bf16x8;
typedef __attribute__((ext_vector_type(4))) float f32x4;

// fp32 -> bf16 round-to-nearest-even (finite inputs), pure bit math
__device__ inline unsigned short f2bf(float f) {
    unsigned u = __builtin_bit_cast(unsigned, f);
    return (unsigned short)((u + 0x7FFFu + ((u >> 16) & 1u)) >> 16);
}
__device__ inline unsigned pk2(float lo, float hi) {
    return (unsigned)f2bf(lo) | ((unsigned)f2bf(hi) << 16);
}

// ---------------------------------------------------------------------------
// Kernel 1: self_feat = feat @ W_feat + b_feat ; pre_byp = feat @ W_byp
// ---------------------------------------------------------------------------
__global__ __launch_bounds__(256) void linear1_k(
    const float* __restrict__ feat, const float* __restrict__ Wf,
    const float* __restrict__ bf,   const float* __restrict__ Wb,
    float* __restrict__ selfF, float* __restrict__ preB)
{
    const int t  = threadIdx.x;
    const int r0 = blockIdx.x * 64;
    const bool isF = (t < 64);
    const int o = isF ? t : (t - 64);

    float wcol[64];
    if (isF) {
        #pragma unroll
        for (int k = 0; k < 64; ++k) wcol[k] = Wf[k*64 + o];
    } else {
        #pragma unroll
        for (int k = 0; k < 64; ++k) wcol[k] = Wb[k*192 + o];
    }
    const float bias = isF ? bf[o] : 0.0f;

    for (int rr = 0; rr < 64; ++rr) {
        const int r = r0 + rr;
        const float* __restrict__ fr = feat + (size_t)r * 64;
        float a = bias;
        #pragma unroll
        for (int k = 0; k < 64; ++k) a = fmaf(wcol[k], fr[k], a);
        if (isF) selfF[(size_t)r*64  + o] = a;
        else     preB [(size_t)r*192 + o] = a;
    }
}

// ---------------------------------------------------------------------------
// xyz [b][j][3] -> xT [b][3][j]   (for contiguous per-lane j-coord loads)
// ---------------------------------------------------------------------------
__global__ __launch_bounds__(256) void xyzT_k(const float* __restrict__ xyz,
                                              float* __restrict__ xT)
{
    const int t = blockIdx.x * 256 + threadIdx.x;
    if (t < NB*NPTS) {
        const int b = t >> 11, j = t & (NPTS-1);
        const float* p = xyz + (size_t)t * 3;
        xT[((size_t)b*3 + 0)*NPTS + j] = p[0];
        xT[((size_t)b*3 + 1)*NPTS + j] = p[1];
        xT[((size_t)b*3 + 2)*NPTS + j] = p[2];
    }
}

// ---------------------------------------------------------------------------
// Per-channel sum / sumsq (training BN stats), atomic accumulate.
// ---------------------------------------------------------------------------
template<int C, int R>
__global__ __launch_bounds__(256) void stats_k(const float* __restrict__ X, int Mrows,
                                               float* __restrict__ osum, float* __restrict__ osq)
{
    __shared__ float l1[256];
    __shared__ float l2[256];
    const int t = threadIdx.x;
    float ps = 0.0f, pq = 0.0f;
    if (t < C*R) {
        const int c  = t % C;
        const int ro = t / C;
        for (int r = blockIdx.x * R + ro; r < Mrows; r += gridDim.x * R) {
            const float v = X[(size_t)r*C + c];
            ps += v; pq += v*v;
        }
    }
    l1[t] = ps; l2[t] = pq;
    __syncthreads();
    if (t < C) {
        #pragma unroll
        for (int rr = 1; rr < R; ++rr) { ps += l1[t + rr*C]; pq += l2[t + rr*C]; }
        atomicAdd(osum + t, ps);
        atomicAdd(osq  + t, pq);
    }
}

// ---------------------------------------------------------------------------
// BN+relu of pre_byp, emitted directly as PRE-PACKED bf16 B-fragments:
// mTf layout (shorts): [b][js(64)][g(6)][h(2)][lane(64)][e(8)]
//   value = m[j = js*32 + (lane>>4)*8 + e][c = g*32 + h*16 + (lane&15)]
// ---------------------------------------------------------------------------
__global__ __launch_bounds__(256) void bn_t192_k(
    const float* __restrict__ sum, const float* __restrict__ sq,
    const float* __restrict__ g,   const float* __restrict__ be,
    const float* __restrict__ X,   unsigned short* __restrict__ mTf)
{
    __shared__ unsigned short tile[32][68];
    const int bid = blockIdx.x;
    const int grp = bid % 6;
    const int jb  = (bid / 6) % 32;
    const int b   = bid / 192;
    const int t   = threadIdx.x;

    const int c = grp*32 + (t & 31);
    const float invM = 1.0f / (float)MROWS;
    const float mu  = sum[c] * invM;
    const float var = sq[c] * invM - mu*mu;
    const float sc  = g[c] * rsqrtf(var + BN_EPS);
    const float sh  = be[c] - mu * sc;

    const float* __restrict__ Xb = X + ((size_t)b*NPTS + jb*64) * 192;
    #pragma unroll
    for (int rr = 0; rr < 8; ++rr) {
        const int j = (t >> 5) + rr*8;
        float v = Xb[(size_t)j*192 + c];
        v = fmaxf(fmaf(v, sc, sh), 0.0f);
        tile[t & 31][j] = f2bf(v);
    }
    __syncthreads();

    const int lane = t & 63;
    const int h    = (t >> 6) & 1;
    const int s    = t >> 7;
    const unsigned short* tp = &tile[h*16 + (lane & 15)][s*32 + ((lane >> 4) & 3)*8];
    uint2 lo = *(const uint2*)tp;
    uint2 hi = *(const uint2*)(tp + 4);
    uint4 o = { lo.x, lo.y, hi.x, hi.y };
    const int js = jb*2 + s;
    unsigned short* dst = mTf + ((((size_t)(b*64 + js)*6 + grp)*2 + h)*64 + lane)*8;
    *(uint4*)dst = o;
}

// ---------------------------------------------------------------------------
// MFMA aggregate. Block = 4 waves, i-tile of 16 (shared), j split 4x512.
// ---------------------------------------------------------------------------
__global__ __launch_bounds__(256) void aggregate_mfma_k(
    const unsigned short* __restrict__ mTf,
    const float* __restrict__ xT,
    float* __restrict__ ag)
{
    __shared__ float lacc[4][16][32];
    __shared__ float lnorm[4][16];

    const int bid = blockIdx.x;
    const int swz = (bid & 7) * 256 + (bid >> 3);   // bijective for 2048
    const int b   = swz >> 7;
    const int i0  = (swz & 127) << 4;
    const int t    = threadIdx.x;
    const int lane = t & 63;
    const int w    = t >> 6;
    const int irow = lane & 15;
    const int kgrp = lane >> 4;

    const float* __restrict__ xb = xT + (size_t)b * 3 * NPTS;
    const unsigned short* __restrict__ mb = mTf + (size_t)b * 64 * 12 * 512;

    const float xi = xb[0*NPTS + i0 + irow];
    const float yi = xb[1*NPTS + i0 + irow];
    const float zi = xb[2*NPTS + i0 + irow];

    f32x4 acc0 = {0.f,0.f,0.f,0.f};
    f32x4 acc1 = {0.f,0.f,0.f,0.f};
    float nrm = 0.0f;

    const float r2    = 0.15f*0.15f;
    const float dr2   = 0.30f*0.30f;
    const float invdr = 1.0f / (dr2 - r2);
    const float drc   = dr2 * invdr;

    const int jbase = w * 512;
    for (int j0 = jbase; j0 < jbase + 512; j0 += 32) {
        const int jj = j0 + kgrp*8;
        float4 a0 = *(const float4*)(xb + 0*NPTS + jj);
        float4 a1 = *(const float4*)(xb + 0*NPTS + jj + 4);
        float4 b0 = *(const float4*)(xb + 1*NPTS + jj);
        float4 b1 = *(const float4*)(xb + 1*NPTS + jj + 4);
        float4 c0 = *(const float4*)(xb + 2*NPTS + jj);
        float4 c1 = *(const float4*)(xb + 2*NPTS + jj + 4);
        float fx[8] = {a0.x,a0.y,a0.z,a0.w,a1.x,a1.y,a1.z,a1.w};
        float fy[8] = {b0.x,b0.y,b0.z,b0.w,b1.x,b1.y,b1.z,b1.w};
        float fz[8] = {c0.x,c0.y,c0.z,c0.w,c1.x,c1.y,c1.z,c1.w};

        float dxa[8], dya[8], dza[8], inv[8];
        #pragma unroll
        for (int e = 0; e < 8; ++e) {
            const float dx = fx[e]-xi, dy = fy[e]-yi, dz = fz[e]-zi;
            const float d2 = fmaf(dx,dx, fmaf(dy,dy, dz*dz));
            float wd = fminf(fmaxf(fmaf(d2, -invdr, drc), 0.0f), 1.0f);
            wd = (d2 > 0.0f) ? wd : 0.0f;
            nrm += wd;
            dxa[e] = dx; dya[e] = dy; dza[e] = dz;
            inv[e] = wd * __builtin_amdgcn_rcpf(fmaxf(d2, 1e-12f));
        }

        const unsigned short* sb = mb + (size_t)(j0 >> 5) * 12 * 512 + lane*8;
        #pragma unroll
        for (int ax = 0; ax < 3; ++ax) {
            const float* da = (ax == 0) ? dxa : (ax == 1) ? dya : dza;
            float wp[8], wn[8];
            #pragma unroll
            for (int e = 0; e < 8; ++e) {
                const float wa = da[e]*da[e]*inv[e];
                const float p  = (da[e] > 0.0f) ? wa : 0.0f;
                wp[e] = p; wn[e] = wa - p;
            }
            union { bf16x8 v; unsigned u[4]; } Ap, An;
            #pragma unroll
            for (int p = 0; p < 4; ++p) {
                Ap.u[p] = pk2(wp[2*p], wp[2*p+1]);
                An.u[p] = pk2(wn[2*p], wn[2*p+1]);
            }
            const bf16x8 Bp0 = *(const bf16x8*)(sb + (size_t)((2*ax  )*2    )*512);
            const bf16x8 Bp1 = *(const bf16x8*)(sb + (size_t)((2*ax  )*2 + 1)*512);
            const bf16x8 Bn0 = *(const bf16x8*)(sb + (size_t)((2*ax+1)*2    )*512);
            const bf16x8 Bn1 = *(const bf16x8*)(sb + (size_t)((2*ax+1)*2 + 1)*512);
            acc0 = __builtin_amdgcn_mfma_f32_16x16x32_bf16(Ap.v, Bp0, acc0, 0,0,0);
            acc1 = __builtin_amdgcn_mfma_f32_16x16x32_bf16(Ap.v, Bp1, acc1, 0,0,0);
            acc0 = __builtin_amdgcn_mfma_f32_16x16x32_bf16(An.v, Bn0, acc0, 0,0,0);
            acc1 = __builtin_amdgcn_mfma_f32_16x16x32_bf16(An.v, Bn1, acc1, 0,0,0);
        }
    }

    nrm += __shfl_xor(nrm, 16);
    nrm += __shfl_xor(nrm, 32);

    #pragma unroll
    for (int r = 0; r < 4; ++r) {
        lacc[w][kgrp*4 + r][irow]      = acc0[r];
        lacc[w][kgrp*4 + r][16 + irow] = acc1[r];
    }
    if (lane < 16) lnorm[w][lane] = nrm;
    __syncthreads();

    #pragma unroll
    for (int rep = 0; rep < 2; ++rep) {
        const int idx = t + rep*256;
        const int i = idx >> 5, c = idx & 31;
        const float s = lacc[0][i][c] + lacc[1][i][c] + lacc[2][i][c] + lacc[3][i][c];
        const float n = lnorm[0][i] + lnorm[1][i] + lnorm[2][i] + lnorm[3][i];
        ag[((size_t)b*NPTS + i0 + i)*32 + c] = s * __builtin_amdgcn_rcpf(fmaxf(n, 1e-12f));
    }
}

// ---------------------------------------------------------------------------
// BN+relu elementwise (fp32, for C=32 and C=64 stages)
// ---------------------------------------------------------------------------
template<int C>
__global__ __launch_bounds__(256) void bn_relu_k(
    const float* __restrict__ sum, const float* __restrict__ sq,
    const float* __restrict__ g,   const float* __restrict__ be,
    const float* __restrict__ X, float* __restrict__ Y, int n4)
{
    __shared__ __align__(16) float ssc[C];
    __shared__ __align__(16) float ssh[C];
    const int t = threadIdx.x;
    if (t < C) {
        const float invM = 1.0f / (float)MROWS;
        const float mu  = sum[t] * invM;
        const float var = sq[t] * invM - mu*mu;
        const float sc  = g[t] * rsqrtf(var + BN_EPS);
        ssc[t] = sc;
        ssh[t] = be[t] - mu * sc;
    }
    __syncthreads();
    const float4* __restrict__ X4 = (const float4*)X;
    float4* __restrict__ Y4 = (float4*)Y;
    const int stride = gridDim.x * 256;
    for (int i = blockIdx.x*256 + t; i < n4; i += stride) {
        const int c4 = i % (C/4);
        float4 v = X4[i];
        const float4 sc = ((const float4*)ssc)[c4];
        const float4 sh = ((const float4*)ssh)[c4];
        v.x = fmaxf(fmaf(v.x, sc.x, sh.x), 0.0f);
        v.y = fmaxf(fmaf(v.y, sc.y, sh.y), 0.0f);
        v.z = fmaxf(fmaf(v.z, sc.z, sh.z), 0.0f);
        v.w = fmaxf(fmaf(v.w, sc.w, sh.w), 0.0f);
        Y4[i] = v;
    }
}

// ---------------------------------------------------------------------------
// pre2 = bn1relu(ag) @ W_ag + b_ag + self_feat
// ---------------------------------------------------------------------------
__global__ __launch_bounds__(256) void linear2_k(
    const float* __restrict__ agbn, const float* __restrict__ Wag,
    const float* __restrict__ bag,  const float* __restrict__ selfF,
    float* __restrict__ pre2)
{
    const int t  = threadIdx.x;
    const int o  = t & 63;
    const int wu = __builtin_amdgcn_readfirstlane(t >> 6);
    const int r0 = blockIdx.x * 64 + wu * 16;

    float wcol[32];
    #pragma unroll
    for (int k = 0; k < 32; ++k) wcol[k] = Wag[k*64 + o];
    const float bias = bag[o];

    for (int rr = 0; rr < 16; ++rr) {
        const int r = r0 + rr;
        const float* __restrict__ ar = agbn + (size_t)r * 32;
        float a = bias + selfF[(size_t)r*64 + o];
        #pragma unroll
        for (int k = 0; k < 32; ++k) a = fmaf(wcol[k], ar[k], a);
        pre2[(size_t)r*64 + o] = a;
    }
}

// ---------------------------------------------------------------------------
extern "C" void kernel_launch(void* const* d_in, const int* in_sizes, int n_in,
                              void* d_out, int out_size, void* d_ws, size_t ws_size,
                              hipStream_t stream)
{
    const float* feat = (const float*)d_in[0];
    const float* xyz  = (const float*)d_in[1];
    const float* Wf   = (const float*)d_in[2];
    const float* bf   = (const float*)d_in[3];
    const float* Wb   = (const float*)d_in[4];
    const float* gby  = (const float*)d_in[5];
    const float* beby = (const float*)d_in[6];
    const float* g1   = (const float*)d_in[7];
    const float* be1  = (const float*)d_in[8];
    const float* Wag  = (const float*)d_in[9];
    const float* bag  = (const float*)d_in[10];
    const float* g2   = (const float*)d_in[11];
    const float* be2  = (const float*)d_in[12];

    float* ws = (float*)d_ws;
    float* stats = ws;                                  // 1024 f
    float* A   = ws + 1024;                             // self_feat [32768][64]
    float* B   = A + (size_t)MROWS*64;                  // pre_byp   [32768][192]
    float* C   = B + (size_t)MROWS*192;                 // ag        [32768][32]
    float* xT  = C + (size_t)MROWS*32;                  // [16][3][2048]
    unsigned short* mTf = (unsigned short*)(xT + (size_t)NB*3*NPTS);
    float* D = B;                                       // pre2 reuses B

    float* s192s = stats;       float* s192q = stats + 192;
    float* s32s  = stats + 384; float* s32q  = stats + 416;
    float* s64s  = stats + 448; float* s64q  = stats + 512;

    (void)hipMemsetAsync(stats, 0, 1024 * sizeof(float), stream);

    xyzT_k<<<128, 256, 0, stream>>>(xyz, xT);
    linear1_k<<<512, 256, 0, stream>>>(feat, Wf, bf, Wb, A, B);

    stats_k<192,1><<<256, 256, 0, stream>>>(B, MROWS, s192s, s192q);
    bn_t192_k<<<3072, 256, 0, stream>>>(s192s, s192q, gby, beby, B, mTf);

    aggregate_mfma_k<<<2048, 256, 0, stream>>>(mTf, xT, C);

    stats_k<32,8><<<256, 256, 0, stream>>>(C, MROWS, s32s, s32q);
    bn_relu_k<32><<<256, 256, 0, stream>>>(s32s, s32q, g1, be1, C, C, MROWS*32/4);

    linear2_k<<<512, 256, 0, stream>>>(C, Wag, bag, A, D);

    stats_k<64,4><<<256, 256, 0, stream>>>(D, MROWS, s64s, s64q);
    bn_relu_k<64><<<512, 256, 0, stream>>>(s64s, s64q, g2, be2, D, (float*)d_out, MROWS*64/4);
}

// Round 4
// 194.959 us; speedup vs baseline: 2.5918x; 1.2464x over previous
//
#include <hip/hip_runtime.h>
#include <cstddef>

#define NPTS   2048
#define NB     16
#define MROWS  (NPTS*NB)   // 32768
#define BN_EPS 1e-5f

typedef __attribute__((ext_vector_type(8))) short bf16x8;
typedef __attribute__((ext_vector_type(4))) float f32x4;

// fp32 -> bf16 RNE, scalar bit math (used in non-hot transpose kernel)
__device__ inline unsigned short f2bf(float f) {
    unsigned u = __builtin_bit_cast(unsigned, f);
    return (unsigned short)((u + 0x7FFFu + ((u >> 16) & 1u)) >> 16);
}
// HW packed convert: dst = {lo16: bf16(a), hi16: bf16(b)} — 1 VALU instr
__device__ inline unsigned cvtpk(float a, float b) {
    unsigned r;
    asm("v_cvt_pk_bf16_f32 %0, %1, %2" : "=v"(r) : "v"(a), "v"(b));
    return r;
}

// ---------------------------------------------------------------------------
// linear1 + fused BN stats of the byp half:
//   selfF = feat @ W_feat + b_feat ; preB = feat @ W_byp ; s192 = Σ preB, Σ preB²
// ---------------------------------------------------------------------------
__global__ __launch_bounds__(256) void linear1_k(
    const float* __restrict__ feat, const float* __restrict__ Wf,
    const float* __restrict__ bf,   const float* __restrict__ Wb,
    float* __restrict__ selfF, float* __restrict__ preB,
    float* __restrict__ s192s, float* __restrict__ s192q)
{
    const int t  = threadIdx.x;
    const int r0 = blockIdx.x * 64;
    const bool isF = (t < 64);
    const int o = isF ? t : (t - 64);

    float wcol[64];
    if (isF) {
        #pragma unroll
        for (int k = 0; k < 64; ++k) wcol[k] = Wf[k*64 + o];
    } else {
        #pragma unroll
        for (int k = 0; k < 64; ++k) wcol[k] = Wb[k*192 + o];
    }
    const float bias = isF ? bf[o] : 0.0f;

    float ps = 0.0f, pq = 0.0f;
    for (int rr = 0; rr < 64; ++rr) {
        const int r = r0 + rr;
        const float* __restrict__ fr = feat + (size_t)r * 64;
        float a = bias;
        #pragma unroll
        for (int k = 0; k < 64; ++k) a = fmaf(wcol[k], fr[k], a);
        if (isF) selfF[(size_t)r*64  + o] = a;
        else {
            preB[(size_t)r*192 + o] = a;
            ps += a; pq = fmaf(a, a, pq);
        }
    }
    if (!isF) {
        atomicAdd(s192s + o, ps);
        atomicAdd(s192q + o, pq);
    }
}

// ---------------------------------------------------------------------------
// xyz [b][j][3] -> xT [b][3][j]
// ---------------------------------------------------------------------------
__global__ __launch_bounds__(256) void xyzT_k(const float* __restrict__ xyz,
                                              float* __restrict__ xT)
{
    const int t = blockIdx.x * 256 + threadIdx.x;
    if (t < NB*NPTS) {
        const int b = t >> 11, j = t & (NPTS-1);
        const float* p = xyz + (size_t)t * 3;
        xT[((size_t)b*3 + 0)*NPTS + j] = p[0];
        xT[((size_t)b*3 + 1)*NPTS + j] = p[1];
        xT[((size_t)b*3 + 2)*NPTS + j] = p[2];
    }
}

// ---------------------------------------------------------------------------
// BN+relu of pre_byp -> pre-packed bf16 B-fragments
// mTf layout (shorts): [b][js(64)][g(6)][h(2)][lane(64)][e(8)]
//   value = m[j = js*32 + (lane>>4)*8 + e][c = g*32 + h*16 + (lane&15)]
// ---------------------------------------------------------------------------
__global__ __launch_bounds__(256) void bn_t192_k(
    const float* __restrict__ sum, const float* __restrict__ sq,
    const float* __restrict__ g,   const float* __restrict__ be,
    const float* __restrict__ X,   unsigned short* __restrict__ mTf)
{
    __shared__ unsigned short tile[32][68];
    const int bid = blockIdx.x;
    const int grp = bid % 6;
    const int jb  = (bid / 6) % 32;
    const int b   = bid / 192;
    const int t   = threadIdx.x;

    const int c = grp*32 + (t & 31);
    const float invM = 1.0f / (float)MROWS;
    const float mu  = sum[c] * invM;
    const float var = sq[c] * invM - mu*mu;
    const float sc  = g[c] * rsqrtf(var + BN_EPS);
    const float sh  = be[c] - mu * sc;

    const float* __restrict__ Xb = X + ((size_t)b*NPTS + jb*64) * 192;
    #pragma unroll
    for (int rr = 0; rr < 8; ++rr) {
        const int j = (t >> 5) + rr*8;
        float v = Xb[(size_t)j*192 + c];
        v = fmaxf(fmaf(v, sc, sh), 0.0f);
        tile[t & 31][j] = f2bf(v);
    }
    __syncthreads();

    const int lane = t & 63;
    const int h    = (t >> 6) & 1;
    const int s    = t >> 7;
    const unsigned short* tp = &tile[h*16 + (lane & 15)][s*32 + ((lane >> 4) & 3)*8];
    uint2 lo = *(const uint2*)tp;
    uint2 hi = *(const uint2*)(tp + 4);
    uint4 o = { lo.x, lo.y, hi.x, hi.y };
    const int js = jb*2 + s;
    unsigned short* dst = mTf + ((((size_t)(b*64 + js)*6 + grp)*2 + h)*64 + lane)*8;
    *(uint4*)dst = o;
}

// ---------------------------------------------------------------------------
// MFMA aggregate, v2: block = 4 waves, TWO 16-row i-tiles (32 i's),
// j split 4x512. B-fragments loaded once per slice feed both i-tiles.
// Self-pair (j==i, d2==0) contributes 0 to numerator and +1 to norm;
// corrected by subtracting 1 in the epilogue (no per-pair validity mask).
// Fused: BN stats of ag (s32) via per-block column reduction + atomicAdd.
// Grid 1024 = 16 b x 64 tiles, XCD-bijective swizzle -> 2 batches/XCD L2.
// ---------------------------------------------------------------------------
__global__ __launch_bounds__(256) void aggregate_mfma_k(
    const unsigned short* __restrict__ mTf,
    const float* __restrict__ xT,
    float* __restrict__ ag,
    float* __restrict__ s32s, float* __restrict__ s32q)
{
    __shared__ float lacc[4][32][32];
    __shared__ float lnorm[4][32];

    const int bid = blockIdx.x;
    const int swz = (bid & 7) * 128 + (bid >> 3);   // bijective for 1024
    const int b   = swz >> 6;                       // 0..15
    const int i0  = (swz & 63) << 5;                // 0..2047 step 32
    const int t    = threadIdx.x;
    const int lane = t & 63;
    const int w    = t >> 6;
    const int iloc = lane & 15;    // A-row within 16-tile (also D col index)
    const int kgrp = lane >> 4;

    const float* __restrict__ xb = xT + (size_t)b * 3 * NPTS;
    const unsigned short* __restrict__ mb = mTf + (size_t)b * 64 * 12 * 512;

    const float xi0 = xb[0*NPTS + i0 + iloc],      yi0 = xb[1*NPTS + i0 + iloc],      zi0 = xb[2*NPTS + i0 + iloc];
    const float xi1 = xb[0*NPTS + i0 + 16 + iloc], yi1 = xb[1*NPTS + i0 + 16 + iloc], zi1 = xb[2*NPTS + i0 + 16 + iloc];

    f32x4 acc[2][2];
    #pragma unroll
    for (int a = 0; a < 2; ++a)
        #pragma unroll
        for (int h = 0; h < 2; ++h) acc[a][h] = f32x4{0.f,0.f,0.f,0.f};
    float nrm0 = 0.0f, nrm1 = 0.0f;

    const float r2    = 0.15f*0.15f;
    const float dr2   = 0.30f*0.30f;
    const float invdr = 1.0f / (dr2 - r2);
    const float drc   = dr2 * invdr;

    const int jbase = w * 512;
    for (int j0 = jbase; j0 < jbase + 512; j0 += 32) {
        const int jj = j0 + kgrp*8;
        float fx[8], fy[8], fz[8];
        *(float4*)&fx[0] = *(const float4*)(xb + 0*NPTS + jj);
        *(float4*)&fx[4] = *(const float4*)(xb + 0*NPTS + jj + 4);
        *(float4*)&fy[0] = *(const float4*)(xb + 1*NPTS + jj);
        *(float4*)&fy[4] = *(const float4*)(xb + 1*NPTS + jj + 4);
        *(float4*)&fz[0] = *(const float4*)(xb + 2*NPTS + jj);
        *(float4*)&fz[4] = *(const float4*)(xb + 2*NPTS + jj + 4);

        unsigned pw[2][6][4];
        #pragma unroll
        for (int it = 0; it < 2; ++it) {
            const float xi = it ? xi1 : xi0;
            const float yi = it ? yi1 : yi0;
            const float zi = it ? zi1 : zi0;
            float dxa[8], dya[8], dza[8], inv[8];
            #pragma unroll
            for (int e = 0; e < 8; ++e) {
                const float dx = fx[e]-xi, dy = fy[e]-yi, dz = fz[e]-zi;
                const float d2 = fmaf(dx,dx, fmaf(dy,dy, dz*dz));
                const float wd = fminf(fmaxf(fmaf(d2, -invdr, drc), 0.0f), 1.0f);
                if (it) nrm1 += wd; else nrm0 += wd;
                dxa[e] = dx; dya[e] = dy; dza[e] = dz;
                inv[e] = wd * __builtin_amdgcn_rcpf(fmaxf(d2, 1e-12f));
            }
            #pragma unroll
            for (int ax = 0; ax < 3; ++ax) {
                const float* da = (ax == 0) ? dxa : (ax == 1) ? dya : dza;
                float wp[8], wn[8];
                #pragma unroll
                for (int e = 0; e < 8; ++e) {
                    const float wa = da[e]*da[e]*inv[e];
                    const float p  = (da[e] > 0.0f) ? wa : 0.0f;
                    wp[e] = p; wn[e] = wa - p;
                }
                #pragma unroll
                for (int p = 0; p < 4; ++p) {
                    pw[it][2*ax  ][p] = cvtpk(wp[2*p], wp[2*p+1]);
                    pw[it][2*ax+1][p] = cvtpk(wn[2*p], wn[2*p+1]);
                }
            }
        }

        const unsigned short* sb = mb + (size_t)(j0 >> 5) * 12 * 512 + lane*8;
        #pragma unroll
        for (int gp = 0; gp < 6; ++gp) {
            #pragma unroll
            for (int h = 0; h < 2; ++h) {
                const bf16x8 B = *(const bf16x8*)(sb + (size_t)(gp*2 + h)*512);
                const bf16x8 A0 = __builtin_bit_cast(bf16x8, *(uint4*)&pw[0][gp][0]);
                const bf16x8 A1 = __builtin_bit_cast(bf16x8, *(uint4*)&pw[1][gp][0]);
                acc[0][h] = __builtin_amdgcn_mfma_f32_16x16x32_bf16(A0, B, acc[0][h], 0,0,0);
                acc[1][h] = __builtin_amdgcn_mfma_f32_16x16x32_bf16(A1, B, acc[1][h], 0,0,0);
            }
        }
    }

    // sum the 4 kgrp copies of each i's norm
    nrm0 += __shfl_xor(nrm0, 16);  nrm0 += __shfl_xor(nrm0, 32);
    nrm1 += __shfl_xor(nrm1, 16);  nrm1 += __shfl_xor(nrm1, 32);

    // D layout: col = lane&15 (= channel here), row = kgrp*4 + reg (= i-local)
    #pragma unroll
    for (int it = 0; it < 2; ++it)
        #pragma unroll
        for (int r = 0; r < 4; ++r) {
            lacc[w][it*16 + kgrp*4 + r][iloc]      = acc[it][0][r];
            lacc[w][it*16 + kgrp*4 + r][16 + iloc] = acc[it][1][r];
        }
    if (lane < 16) { lnorm[w][lane] = nrm0; lnorm[w][16 + lane] = nrm1; }
    __syncthreads();

    // final: normalize (norm minus self-pair), write, stash val for stats
    #pragma unroll
    for (int rep = 0; rep < 4; ++rep) {
        const int idx = t + rep*256;
        const int i = idx >> 5, c = idx & 31;
        const float s = lacc[0][i][c] + lacc[1][i][c] + lacc[2][i][c] + lacc[3][i][c];
        const float n = lnorm[0][i] + lnorm[1][i] + lnorm[2][i] + lnorm[3][i] - 1.0f;
        const float val = s * __builtin_amdgcn_rcpf(fmaxf(n, 1e-12f));
        ag[((size_t)b*NPTS + i0 + i)*32 + c] = val;
        lacc[0][i][c] = val;                  // each (i,c) owned by one thread
    }
    __syncthreads();
    if (t < 32) {
        float ps = 0.0f, pq = 0.0f;
        #pragma unroll
        for (int i = 0; i < 32; ++i) {
            const float v = lacc[0][i][t];
            ps += v; pq = fmaf(v, v, pq);
        }
        atomicAdd(s32s + t, ps);
        atomicAdd(s32q + t, pq);
    }
}

// ---------------------------------------------------------------------------
// Fused: bn1relu(ag) (from s32 stats) -> LDS; pre2 = lds @ W_ag + b_ag + selfF;
// fused BN stats of pre2 (s64). Block = 64 rows.
// ---------------------------------------------------------------------------
__global__ __launch_bounds__(256) void lin2f_k(
    const float* __restrict__ ag,
    const float* __restrict__ s32s, const float* __restrict__ s32q,
    const float* __restrict__ g1,   const float* __restrict__ be1,
    const float* __restrict__ Wag,  const float* __restrict__ bag,
    const float* __restrict__ selfF,
    float* __restrict__ pre2,
    float* __restrict__ s64s, float* __restrict__ s64q)
{
    __shared__ float lds[64][32];
    __shared__ float sc_[32], sh_[32];
    __shared__ float red[8][64];
    const int t  = threadIdx.x;
    const int r0 = blockIdx.x * 64;

    if (t < 32) {
        const float invM = 1.0f / (float)MROWS;
        const float mu  = s32s[t] * invM;
        const float var = s32q[t] * invM - mu*mu;
        const float sc  = g1[t] * rsqrtf(var + BN_EPS);
        sc_[t] = sc; sh_[t] = be1[t] - mu * sc;
    }
    __syncthreads();
    {
        const int r = t >> 2, c0 = (t & 3) * 8;
        const float* src = ag + ((size_t)(r0 + r))*32 + c0;
        float4 v0 = *(const float4*)src;
        float4 v1 = *(const float4*)(src + 4);
        float v[8] = {v0.x,v0.y,v0.z,v0.w,v1.x,v1.y,v1.z,v1.w};
        #pragma unroll
        for (int e = 0; e < 8; ++e)
            lds[r][c0 + e] = fmaxf(fmaf(v[e], sc_[c0 + e], sh_[c0 + e]), 0.0f);
    }
    __syncthreads();

    const int o = t & 63, wu = t >> 6;
    float wcol[32];
    #pragma unroll
    for (int k = 0; k < 32; ++k) wcol[k] = Wag[k*64 + o];
    const float bias = bag[o];

    float ds = 0.0f, dq = 0.0f;
    #pragma unroll 4
    for (int rr = 0; rr < 16; ++rr) {
        const int r = wu*16 + rr;
        float a = bias + selfF[((size_t)(r0 + r))*64 + o];
        #pragma unroll
        for (int k = 0; k < 32; ++k) a = fmaf(wcol[k], lds[r][k], a);
        pre2[((size_t)(r0 + r))*64 + o] = a;
        ds += a; dq = fmaf(a, a, dq);
    }
    red[wu*2 + 0][o] = ds;
    red[wu*2 + 1][o] = dq;
    __syncthreads();
    if (t < 64) {
        const float s = red[0][t] + red[2][t] + red[4][t] + red[6][t];
        const float q = red[1][t] + red[3][t] + red[5][t] + red[7][t];
        atomicAdd(s64s + t, s);
        atomicAdd(s64q + t, q);
    }
}

// ---------------------------------------------------------------------------
// Final BN+relu (C=64) -> d_out
// ---------------------------------------------------------------------------
template<int C>
__global__ __launch_bounds__(256) void bn_relu_k(
    const float* __restrict__ sum, const float* __restrict__ sq,
    const float* __restrict__ g,   const float* __restrict__ be,
    const float* __restrict__ X, float* __restrict__ Y, int n4)
{
    __shared__ __align__(16) float ssc[C];
    __shared__ __align__(16) float ssh[C];
    const int t = threadIdx.x;
    if (t < C) {
        const float invM = 1.0f / (float)MROWS;
        const float mu  = sum[t] * invM;
        const float var = sq[t] * invM - mu*mu;
        const float sc  = g[t] * rsqrtf(var + BN_EPS);
        ssc[t] = sc;
        ssh[t] = be[t] - mu * sc;
    }
    __syncthreads();
    const float4* __restrict__ X4 = (const float4*)X;
    float4* __restrict__ Y4 = (float4*)Y;
    const int stride = gridDim.x * 256;
    for (int i = blockIdx.x*256 + t; i < n4; i += stride) {
        const int c4 = i % (C/4);
        float4 v = X4[i];
        const float4 sc = ((const float4*)ssc)[c4];
        const float4 sh = ((const float4*)ssh)[c4];
        v.x = fmaxf(fmaf(v.x, sc.x, sh.x), 0.0f);
        v.y = fmaxf(fmaf(v.y, sc.y, sh.y), 0.0f);
        v.z = fmaxf(fmaf(v.z, sc.z, sh.z), 0.0f);
        v.w = fmaxf(fmaf(v.w, sc.w, sh.w), 0.0f);
        Y4[i] = v;
    }
}

// ---------------------------------------------------------------------------
extern "C" void kernel_launch(void* const* d_in, const int* in_sizes, int n_in,
                              void* d_out, int out_size, void* d_ws, size_t ws_size,
                              hipStream_t stream)
{
    const float* feat = (const float*)d_in[0];
    const float* xyz  = (const float*)d_in[1];
    const float* Wf   = (const float*)d_in[2];
    const float* bf   = (const float*)d_in[3];
    const float* Wb   = (const float*)d_in[4];
    const float* gby  = (const float*)d_in[5];
    const float* beby = (const float*)d_in[6];
    const float* g1   = (const float*)d_in[7];
    const float* be1  = (const float*)d_in[8];
    const float* Wag  = (const float*)d_in[9];
    const float* bag  = (const float*)d_in[10];
    const float* g2   = (const float*)d_in[11];
    const float* be2  = (const float*)d_in[12];

    float* ws = (float*)d_ws;
    float* stats = ws;                                  // 1024 f
    float* A   = ws + 1024;                             // self_feat [32768][64]
    float* B   = A + (size_t)MROWS*64;                  // pre_byp   [32768][192]
    float* C   = B + (size_t)MROWS*192;                 // ag        [32768][32]
    float* xT  = C + (size_t)MROWS*32;                  // [16][3][2048]
    unsigned short* mTf = (unsigned short*)(xT + (size_t)NB*3*NPTS);
    float* D = B;                                       // pre2 reuses B

    float* s192s = stats;       float* s192q = stats + 192;
    float* s32s  = stats + 384; float* s32q  = stats + 416;
    float* s64s  = stats + 448; float* s64q  = stats + 512;

    (void)hipMemsetAsync(stats, 0, 1024 * sizeof(float), stream);

    xyzT_k<<<128, 256, 0, stream>>>(xyz, xT);
    linear1_k<<<512, 256, 0, stream>>>(feat, Wf, bf, Wb, A, B, s192s, s192q);

    bn_t192_k<<<3072, 256, 0, stream>>>(s192s, s192q, gby, beby, B, mTf);

    aggregate_mfma_k<<<1024, 256, 0, stream>>>(mTf, xT, C, s32s, s32q);

    lin2f_k<<<512, 256, 0, stream>>>(C, s32s, s32q, g1, be1, Wag, bag, A, D, s64s, s64q);

    bn_relu_k<64><<<512, 256, 0, stream>>>(s64s, s64q, g2, be2, D, (float*)d_out, MROWS*64/4);
}